// Round 2
// baseline (167.318 us; speedup 1.0000x reference)
//
#include <hip/hip_runtime.h>
#include <hip/hip_fp16.h>

// InteractionBlock, MI355X, round 6.
//
// y = out @ W3 + gathersum(out) @ (W2@W3) + (b2@W3 + b3)
// R5 post-mortem: occupancy 32->50% at CONSTANT 3.27 TB/s and constant
// FETCH=153 MB -> gather is L2-fill-rate limited (~2.7 TB/s fetch ~= 1.1
// 128B-fills/cy/XCD), not latency-bound. The only lever left is fill VOLUME:
// packed (12.8 MB) > 4 MB per-XCD L2 -> capacity thrash; compulsory floor is
// 12.8 x 8 XCD = 102 MB vs 153 measured. R6: segmented sweep. All 1563
// blocks are co-resident (8/CU); every block walks neighbors in 8 global
// segments of 1.6 MB so each XCD's L2 holds only the live segment.
// Match extraction is ballot + s_ff1 + readlane, 4-wide -> 4 independent
// fp16 chains, no extra vector loads, MLP preserved.
// Predict: FETCH 153 -> ~115 MB, fused 57 -> ~45 us.

constexpr int A   = 64;    // ao_vals
constexpr int K   = 32;    // neighbors
constexpr int GPB = 32;    // grid points per block (4 waves x 8)
constexpr int XS  = 136;   // LDS row stride in halves (128 data + 8 pad)
constexpr int NSEG = 8;    // gather segments (1.6 MB each over packed)

typedef _Float16 f16x8 __attribute__((ext_vector_type(8)));
typedef float    f32x4 __attribute__((ext_vector_type(4)));

// ---- kernel 1 (merged prep):
//   blocks [0,16):   WTg[n][k] = (half) concat(W2@W3, W3)[k][n]  (n-major,
//                    128/row) and bb = b2@W3 + b3 (fp32)
//   blocks [16,...): pack out (fp32 [2][G][64]) -> packed ([G+1][64] half2)
//                    dword c of row g: c<32 -> batch0 pair (2c,2c+1); else b1.
//                    Row G is the materialized zero pad row (ws re-poisoned
//                    every launch, so it must be written every launch).
__global__ void prep_kernel(const float* __restrict__ W2, const float* __restrict__ b2,
                            const float* __restrict__ W3, const float* __restrict__ b3,
                            __half* __restrict__ WTg, float* __restrict__ bb,
                            const float2* __restrict__ out2,
                            __half2* __restrict__ packed, const int G) {
  if (blockIdx.x < 16) {
    const int e = blockIdx.x * 256 + threadIdx.x;   // 0..4095
    const int n = e >> 6, k = e & 63;
    float acc = 0.f;
#pragma unroll
    for (int q = 0; q < A; ++q) acc = fmaf(W2[k * A + q], W3[q * A + n], acc);
    WTg[n * 128 + k]     = __float2half(acc);           // W23 part (k rows 0..63)
    WTg[n * 128 + A + k] = __float2half(W3[k * A + n]); // W3 part (k rows 64..127)
    if (blockIdx.x == 0 && threadIdx.x < A) {
      const int t = threadIdx.x;
      float b = b3[t];
#pragma unroll
      for (int q = 0; q < A; ++q) b = fmaf(b2[q], W3[q * A + t], b);
      bb[t] = b;
    }
    return;
  }
  const int d = (blockIdx.x - 16) * 256 + threadIdx.x;
  const int total = (G + 1) * 64;
  if (d >= total) return;
  const int g = d >> 6, c = d & 63;
  float2 v = make_float2(0.f, 0.f);
  if (g < G) {
    const int b = c >> 5;
    v = out2[(size_t)b * (G * 32) + (size_t)g * 32 + (c & 31)];
  }
  packed[d] = __floats2half2_rn(v.x, v.y);
}

// ---- kernel 2: segmented gather-sum + MFMA epilogue. 4 waves, 32 g/block --
// LDS 17.4 KB (X only; WT read from global -> L1). 8 blocks/CU.
__global__ __launch_bounds__(256, 8) void fused_kernel(
    const __half2* __restrict__ packed, const int* __restrict__ nbr,
    const __half* __restrict__ WTg, const float* __restrict__ bb,
    float* __restrict__ y, const int G) {
  __shared__ __half X[64 * XS];   // rows: b*32+gl ; cols: [m(64) | o(64)]

  const int tid = threadIdx.x;
  const int lane = tid & 63;
  const int w = __builtin_amdgcn_readfirstlane(tid >> 6);  // wave id, SGPR
  const int gbase = blockIdx.x * GPB;
  const int gcount = min(GPB, G - gbase);
  const int e = lane & 31;              // element-pair index
  const int rb = (lane >> 5) * 32;      // row base: batch = lane>>5
  const int kl = lane & 31;             // neighbor slot this lane owns

  const __half2 z = __floats2half2_rn(0.f, 0.f);

  // Load this wave's 8x32 neighbor indices into VGPR lanes (lane kl = slot kl;
  // lanes 32-63 duplicate, ballot low-32 bits are authoritative).
  int vidx[8];
#pragma unroll
  for (int gg = 0; gg < 8; ++gg) {
    const int gl = w * 8 + gg;
    const int g = gbase + (gl < gcount ? gl : 0);
    vidx[gg] = nbr[(size_t)g * K + kl];
  }

  __half2 msum[8];
#pragma unroll
  for (int gg = 0; gg < 8; ++gg) msum[gg] = z;

  const int seglen = (G + NSEG) / NSEG;   // covers rows [0, G] incl. pad row

  for (int seg = 0; seg < NSEG; ++seg) {
    const int lo = seg * seglen;
#pragma unroll
    for (int gg = 0; gg < 8; ++gg) {
      const int gl = w * 8 + gg;
      const int g = gbase + (gl < gcount ? gl : 0);
      // Residual row: load it in its home segment (keeps it an L2 hit).
      if (gl < gcount && g >= lo && g < lo + seglen) {
        const int r = rb + gl;
        *(__half2*)&X[r * XS + A + 2 * e] = packed[(size_t)g * 64 + lane];
      }
      const bool inseg = ((unsigned)(vidx[gg] - lo)) < (unsigned)seglen;
      unsigned int mask = (unsigned int)__ballot(inseg);  // uniform, low 32 bits
      __half2 a0 = z, a1 = z, a2 = z, a3 = z;
      while (__popc(mask) >= 4) {
        const int k0 = __builtin_ctz(mask); mask &= mask - 1;
        const int k1 = __builtin_ctz(mask); mask &= mask - 1;
        const int k2 = __builtin_ctz(mask); mask &= mask - 1;
        const int k3 = __builtin_ctz(mask); mask &= mask - 1;
        const int i0 = __builtin_amdgcn_readlane(vidx[gg], k0);
        const int i1 = __builtin_amdgcn_readlane(vidx[gg], k1);
        const int i2 = __builtin_amdgcn_readlane(vidx[gg], k2);
        const int i3 = __builtin_amdgcn_readlane(vidx[gg], k3);
        const __half2 u0 = packed[(size_t)i0 * 64 + lane];
        const __half2 u1 = packed[(size_t)i1 * 64 + lane];
        const __half2 u2 = packed[(size_t)i2 * 64 + lane];
        const __half2 u3 = packed[(size_t)i3 * 64 + lane];
        a0 = __hadd2(a0, u0);
        a1 = __hadd2(a1, u1);
        a2 = __hadd2(a2, u2);
        a3 = __hadd2(a3, u3);
      }
      while (mask) {
        const int k0 = __builtin_ctz(mask); mask &= mask - 1;
        const int i0 = __builtin_amdgcn_readlane(vidx[gg], k0);
        a0 = __hadd2(a0, packed[(size_t)i0 * 64 + lane]);
      }
      msum[gg] = __hadd2(msum[gg], __hadd2(__hadd2(a0, a1), __hadd2(a2, a3)));
    }
  }

#pragma unroll
  for (int gg = 0; gg < 8; ++gg) {
    const int gl = w * 8 + gg;
    if (gl < gcount) {
      const int r = rb + gl;
      *(__half2*)&X[r * XS + 2 * e] = msum[gg];
    }
  }
  __syncthreads();

  // Phase 2: Y[64x64] = X[64x128] @ WcatT^T, wave w does rows w*16..w*16+15.
  // A-frag: A[m=lane&15][k=quad*8+j]; B-frag: B[k=quad*8+j][n=lane&15];
  // C/D: col=lane&15, row=quad*4+reg (HW-verified, dtype-independent).
  // B-frags straight from global WTg (16 KB, identical for all blocks -> L1).
  const int quad = lane >> 4;
  const int mn = lane & 15;
  f32x4 acc0 = {0.f, 0.f, 0.f, 0.f};
  f32x4 acc1 = {0.f, 0.f, 0.f, 0.f};
  f32x4 acc2 = {0.f, 0.f, 0.f, 0.f};
  f32x4 acc3 = {0.f, 0.f, 0.f, 0.f};
#pragma unroll
  for (int kt = 0; kt < 4; ++kt) {
    const int ko = kt * 32 + quad * 8;
    const f16x8 a = *(const f16x8*)&X[(w * 16 + mn) * XS + ko];
    const f16x8 b0 = *(const f16x8*)&WTg[(0 * 16 + mn) * 128 + ko];
    acc0 = __builtin_amdgcn_mfma_f32_16x16x32_f16(a, b0, acc0, 0, 0, 0);
    const f16x8 b1 = *(const f16x8*)&WTg[(1 * 16 + mn) * 128 + ko];
    acc1 = __builtin_amdgcn_mfma_f32_16x16x32_f16(a, b1, acc1, 0, 0, 0);
    const f16x8 b2 = *(const f16x8*)&WTg[(2 * 16 + mn) * 128 + ko];
    acc2 = __builtin_amdgcn_mfma_f32_16x16x32_f16(a, b2, acc2, 0, 0, 0);
    const f16x8 b3 = *(const f16x8*)&WTg[(3 * 16 + mn) * 128 + ko];
    acc3 = __builtin_amdgcn_mfma_f32_16x16x32_f16(a, b3, acc3, 0, 0, 0);
  }

  // Store + bias. Row r = w*16 + quad*4 + reg -> (batch r>>5, gl = r&31).
  f32x4 accs[4] = {acc0, acc1, acc2, acc3};
#pragma unroll
  for (int nt = 0; nt < 4; ++nt) {
    const int col = nt * 16 + mn;
    const float bv = bb[col];
#pragma unroll
    for (int rg = 0; rg < 4; ++rg) {
      const int row = w * 16 + quad * 4 + rg;
      const int b = row >> 5, gl = row & 31;
      if (gl < gcount)
        y[((size_t)b * G + (gbase + gl)) * 64 + col] = accs[nt][rg] + bv;
    }
  }
}

extern "C" void kernel_launch(void* const* d_in, const int* in_sizes, int n_in,
                              void* d_out, int out_size, void* d_ws, size_t ws_size,
                              hipStream_t stream) {
  const float* out = (const float*)d_in[0];
  const int*   nbr = (const int*)d_in[1];
  const float* W2  = (const float*)d_in[2];
  const float* b2  = (const float*)d_in[3];
  const float* W3  = (const float*)d_in[4];
  const float* b3  = (const float*)d_in[5];
  float* y = (float*)d_out;
  const int G = in_sizes[1] / K;

  // ws: packed rows | WTg (fp16 128x64 transposed concat) | bb (fp32 64)
  __half2* packed = (__half2*)d_ws;                       // (G+1)*64 half2
  const size_t packedBytes = (size_t)(G + 1) * 64 * sizeof(__half2);
  __half* WTg = (__half*)((char*)d_ws + packedBytes);     // 8192 halves
  float* bb = (float*)((char*)d_ws + packedBytes + 8192 * sizeof(__half));

  const int packTotal = (G + 1) * 64;
  const int prepBlocks = 16 + (packTotal + 255) / 256;
  prep_kernel<<<prepBlocks, 256, 0, stream>>>(W2, b2, W3, b3, WTg, bb,
                                              (const float2*)out, packed, G);

  const int blocks = (G + GPB - 1) / GPB;
  fused_kernel<<<blocks, 256, 0, stream>>>(packed, nbr, WTg, bb, y, G);
}

// Round 3
// 146.274 us; speedup vs baseline: 1.1439x; 1.1439x over previous
//
#include <hip/hip_runtime.h>
#include <hip/hip_fp16.h>

// InteractionBlock, MI355X, round 7.
//
// y = out @ W3 + gathersum(out) @ (W2@W3) + (b2@W3 + b3)
// R6 post-mortem: segmented sweep DID fix fetch volume (153 -> 69 MB) but the
// ballot/ctz/readlane extraction serialized the gather (data-dependent while
// loops, ~4 loads in flight) -> 82 us, VALUBusy 22%. Locality idea right,
// mechanism wrong. R7: sum is order-invariant -> sort each g's 32 neighbor
// indices ONCE in prep (bitonic over 32 lanes, 15 shfl_xor stages), then run
// the R5 dense gather loop on the sorted lists. Co-resident waves all touch
// index ~ (k/32)*G at the same k -> the ensemble sweeps packed as a moving
// ~2-3 MB band (fits per-XCD L2) with ZERO extraction overhead and full MLP.
// Predict: FETCH ~80-100 MB, fused 57 -> ~35-42 us, VALUBusy ~13%.

constexpr int A   = 64;    // ao_vals
constexpr int K   = 32;    // neighbors
constexpr int GPB = 32;    // grid points per block (4 waves x 8)
constexpr int XS  = 136;   // LDS row stride in halves (128 data + 8 pad)

typedef _Float16 f16x8 __attribute__((ext_vector_type(8)));
typedef float    f32x4 __attribute__((ext_vector_type(4)));

// ---- kernel 1 (merged prep): three block ranges.
//   [0,16):            WTg[n][k] = (half) concat(W2@W3, W3)[k][n] and
//                      bb = b2@W3 + b3 (fp32)
//   [16,16+packB):     pack out (fp32 [2][G][64]) -> packed ([G+1][64] half2)
//                      Row G is the zero pad row (ws re-poisoned every launch).
//   [16+packB,+sortB): nbrs[g][0..31] = sort(nbr[g][0..31]) ascending.
//                      8 rows/block; each 32-lane half-wave runs a bitonic
//                      network (15 shfl_xor compare-exchange stages).
__global__ void prep_kernel(const float* __restrict__ W2, const float* __restrict__ b2,
                            const float* __restrict__ W3, const float* __restrict__ b3,
                            __half* __restrict__ WTg, float* __restrict__ bb,
                            const float2* __restrict__ out2,
                            __half2* __restrict__ packed,
                            const int* __restrict__ nbr, int* __restrict__ nbrs,
                            const int G, const int packB) {
  const int tid = threadIdx.x;
  if (blockIdx.x < 16) {
    const int e = blockIdx.x * 256 + tid;           // 0..4095
    const int n = e >> 6, k = e & 63;
    float acc = 0.f;
#pragma unroll
    for (int q = 0; q < A; ++q) acc = fmaf(W2[k * A + q], W3[q * A + n], acc);
    WTg[n * 128 + k]     = __float2half(acc);           // W23 part (k rows 0..63)
    WTg[n * 128 + A + k] = __float2half(W3[k * A + n]); // W3 part (k rows 64..127)
    if (blockIdx.x == 0 && tid < A) {
      float b = b3[tid];
#pragma unroll
      for (int q = 0; q < A; ++q) b = fmaf(b2[q], W3[q * A + tid], b);
      bb[tid] = b;
    }
    return;
  }
  if (blockIdx.x < 16 + packB) {
    const int d = (blockIdx.x - 16) * 256 + tid;
    const int total = (G + 1) * 64;
    if (d >= total) return;
    const int g = d >> 6, c = d & 63;
    float2 v = make_float2(0.f, 0.f);
    if (g < G) {
      const int b = c >> 5;
      v = out2[(size_t)b * (G * 32) + (size_t)g * 32 + (c & 31)];
    }
    packed[d] = __floats2half2_rn(v.x, v.y);
    return;
  }
  // ---- sort section ----
  const int r = (blockIdx.x - 16 - packB) * 8 + (tid >> 5);  // grid row
  const int slot = tid & 31;
  if (r >= G) return;
  int v = nbr[(size_t)r * K + slot];
#pragma unroll
  for (int k = 2; k <= 32; k <<= 1) {
#pragma unroll
    for (int j = k >> 1; j >= 1; j >>= 1) {
      const int o = __shfl_xor(v, j);               // j<=16: stays in 32-group
      const bool dir = ((slot & k) == 0);           // ascending sub-block?
      const bool takeMin = (((slot & j) == 0) == dir);
      v = takeMin ? min(v, o) : max(v, o);
    }
  }
  nbrs[(size_t)r * K + slot] = v;
}

// ---- kernel 2: gather-sum (sorted indices) + MFMA epilogue. 4 waves/block --
// LDS 17.4 KB (X only; WT read from global -> L1). 8 blocks/CU.
__global__ __launch_bounds__(256, 8) void fused_kernel(
    const __half2* __restrict__ packed, const int* __restrict__ nbrs,
    const __half* __restrict__ WTg, const float* __restrict__ bb,
    float* __restrict__ y, const int G) {
  __shared__ __half X[64 * XS];   // rows: b*32+gl ; cols: [m(64) | o(64)]

  const int tid = threadIdx.x;
  const int lane = tid & 63;
  const int w = __builtin_amdgcn_readfirstlane(tid >> 6);  // wave id, SGPR
  const int gbase = blockIdx.x * GPB;
  const int gcount = min(GPB, G - gbase);
  const int e = lane & 31;              // element-pair index
  const int rb = (lane >> 5) * 32;      // row base: batch = lane>>5

  const __half2 z = __floats2half2_rn(0.f, 0.f);

  // Phase 1: each wave gather-sums 8 grid points (fp16 accumulate, 4 chains).
  // Indices are pre-sorted ascending -> co-resident waves sweep packed as a
  // moving band (emergent segmented sweep, full MLP).
#pragma unroll
  for (int gg = 0; gg < 8; ++gg) {
    const int gl = w * 8 + gg;          // wave-uniform
    if (gl < gcount) {
      const int g = gbase + gl;
      const int* np = nbrs + (size_t)g * K;  // uniform pointer -> s_load indices
      __half2 m0 = z, m1 = z, m2 = z, m3 = z;
#pragma unroll
      for (int k = 0; k < K; k += 4) {
        const __half2 u0 = packed[(size_t)np[k]     * 64 + lane];
        const __half2 u1 = packed[(size_t)np[k + 1] * 64 + lane];
        const __half2 u2 = packed[(size_t)np[k + 2] * 64 + lane];
        const __half2 u3 = packed[(size_t)np[k + 3] * 64 + lane];
        m0 = __hadd2(m0, u0);
        m1 = __hadd2(m1, u1);
        m2 = __hadd2(m2, u2);
        m3 = __hadd2(m3, u3);
      }
      const __half2 m = __hadd2(__hadd2(m0, m1), __hadd2(m2, m3));
      const __half2 o = packed[(size_t)g * 64 + lane];   // residual row
      const int r = rb + gl;
      *(__half2*)&X[r * XS + 2 * e]     = m;
      *(__half2*)&X[r * XS + A + 2 * e] = o;
    }
  }
  __syncthreads();

  // Phase 2: Y[64x64] = X[64x128] @ WcatT^T, wave w does rows w*16..w*16+15.
  // A-frag: A[m=lane&15][k=quad*8+j]; B-frag: B[k=quad*8+j][n=lane&15];
  // C/D: col=lane&15, row=quad*4+reg (HW-verified, dtype-independent).
  // B-frags straight from global WTg (16 KB, identical for all blocks -> L1).
  const int quad = lane >> 4;
  const int mn = lane & 15;
  f32x4 acc0 = {0.f, 0.f, 0.f, 0.f};
  f32x4 acc1 = {0.f, 0.f, 0.f, 0.f};
  f32x4 acc2 = {0.f, 0.f, 0.f, 0.f};
  f32x4 acc3 = {0.f, 0.f, 0.f, 0.f};
#pragma unroll
  for (int kt = 0; kt < 4; ++kt) {
    const int ko = kt * 32 + quad * 8;
    const f16x8 a = *(const f16x8*)&X[(w * 16 + mn) * XS + ko];
    const f16x8 b0 = *(const f16x8*)&WTg[(0 * 16 + mn) * 128 + ko];
    acc0 = __builtin_amdgcn_mfma_f32_16x16x32_f16(a, b0, acc0, 0, 0, 0);
    const f16x8 b1 = *(const f16x8*)&WTg[(1 * 16 + mn) * 128 + ko];
    acc1 = __builtin_amdgcn_mfma_f32_16x16x32_f16(a, b1, acc1, 0, 0, 0);
    const f16x8 b2 = *(const f16x8*)&WTg[(2 * 16 + mn) * 128 + ko];
    acc2 = __builtin_amdgcn_mfma_f32_16x16x32_f16(a, b2, acc2, 0, 0, 0);
    const f16x8 b3 = *(const f16x8*)&WTg[(3 * 16 + mn) * 128 + ko];
    acc3 = __builtin_amdgcn_mfma_f32_16x16x32_f16(a, b3, acc3, 0, 0, 0);
  }

  // Store + bias. Row r = w*16 + quad*4 + reg -> (batch r>>5, gl = r&31).
  f32x4 accs[4] = {acc0, acc1, acc2, acc3};
#pragma unroll
  for (int nt = 0; nt < 4; ++nt) {
    const int col = nt * 16 + mn;
    const float bv = bb[col];
#pragma unroll
    for (int rg = 0; rg < 4; ++rg) {
      const int row = w * 16 + quad * 4 + rg;
      const int b = row >> 5, gl = row & 31;
      if (gl < gcount)
        y[((size_t)b * G + (gbase + gl)) * 64 + col] = accs[nt][rg] + bv;
    }
  }
}

extern "C" void kernel_launch(void* const* d_in, const int* in_sizes, int n_in,
                              void* d_out, int out_size, void* d_ws, size_t ws_size,
                              hipStream_t stream) {
  const float* out = (const float*)d_in[0];
  const int*   nbr = (const int*)d_in[1];
  const float* W2  = (const float*)d_in[2];
  const float* b2  = (const float*)d_in[3];
  const float* W3  = (const float*)d_in[4];
  const float* b3  = (const float*)d_in[5];
  float* y = (float*)d_out;
  const int G = in_sizes[1] / K;

  // ws: packed rows | WTg (fp16 128x64) | bb (fp32 64) | nbrs (sorted int G*K)
  __half2* packed = (__half2*)d_ws;                       // (G+1)*64 half2
  const size_t packedBytes = (size_t)(G + 1) * 64 * sizeof(__half2);
  __half* WTg = (__half*)((char*)d_ws + packedBytes);     // 8192 halves
  float* bb = (float*)((char*)d_ws + packedBytes + 8192 * sizeof(__half));
  int* nbrs = (int*)((char*)d_ws + packedBytes + 8192 * sizeof(__half)
                     + 64 * sizeof(float));

  const int packTotal = (G + 1) * 64;
  const int packB = (packTotal + 255) / 256;
  const int sortB = (G + 7) / 8;
  prep_kernel<<<16 + packB + sortB, 256, 0, stream>>>(
      W2, b2, W3, b3, WTg, bb, (const float2*)out, packed, nbr, nbrs, G, packB);

  const int blocks = (G + GPB - 1) / GPB;
  fused_kernel<<<blocks, 256, 0, stream>>>(packed, nbrs, WTg, bb, y, G);
}

// Round 4
// 139.070 us; speedup vs baseline: 1.2031x; 1.0518x over previous
//
#include <hip/hip_runtime.h>
#include <hip/hip_fp16.h>

// InteractionBlock, MI355X, round 8.
//
// y = out @ W3 + gathersum(out) @ (W2@W3) + (b2@W3 + b3)
// R7 post-mortem: sorting alone changed NOTHING (FETCH exactly 153 MB) --
// the fully-unrolled K-loop issues all 32 loads of a g at once, and a sorted
// 32-sample list still spans the whole table; plus the 8 gg-sweeps per wave
// are serial -> no shared band. R8: loop interchange. Transpose sorted
// indices to nbrsT[block][k][gl] in prep; fused gather outer loop is the
// sweep position k (one s_load_dwordx8 + 8 vloads + 8 pk_adds per step,
// 16 independent fp16 chains), inner loop gg. All co-resident waves now
// target sorted-position k at the same time -> moving ~2 MB band per XCD L2
// (R6 proved 69 MB this way; R8 removes R6's serial extraction).
// Predict: FETCH 153 -> 75-105 MB, fused 57 -> 32-42 us.

constexpr int A   = 64;    // ao_vals
constexpr int K   = 32;    // neighbors
constexpr int GPB = 32;    // grid points per block (4 waves x 8)
constexpr int XS  = 136;   // LDS row stride in halves (128 data + 8 pad)

typedef _Float16 f16x8 __attribute__((ext_vector_type(8)));
typedef float    f32x4 __attribute__((ext_vector_type(4)));

// ---- kernel 1 (merged prep): three block ranges.
//   [0,16):            WTg[n][k] = (half) concat(W2@W3, W3)[k][n] and
//                      bb = b2@W3 + b3 (fp32)
//   [16,16+packB):     pack out (fp32 [2][G][64]) -> packed ([G+1][64] half2)
//                      Row G is the zero pad row (ws re-poisoned every launch).
//   [16+packB,+sortB): per fused block fb: sort each of its 32 rows' 32
//                      neighbor indices ascending (bitonic, 15 shfl_xor
//                      stages) and store TRANSPOSED: nbrsT[fb][k][gl].
//                      Rows beyond G get index G (zero pad row).
__global__ void prep_kernel(const float* __restrict__ W2, const float* __restrict__ b2,
                            const float* __restrict__ W3, const float* __restrict__ b3,
                            __half* __restrict__ WTg, float* __restrict__ bb,
                            const float2* __restrict__ out2,
                            __half2* __restrict__ packed,
                            const int* __restrict__ nbr, int* __restrict__ nbrsT,
                            const int G, const int packB) {
  const int tid = threadIdx.x;
  if (blockIdx.x < 16) {
    const int e = blockIdx.x * 256 + tid;           // 0..4095
    const int n = e >> 6, k = e & 63;
    float acc = 0.f;
#pragma unroll
    for (int q = 0; q < A; ++q) acc = fmaf(W2[k * A + q], W3[q * A + n], acc);
    WTg[n * 128 + k]     = __float2half(acc);           // W23 part (k rows 0..63)
    WTg[n * 128 + A + k] = __float2half(W3[k * A + n]); // W3 part (k rows 64..127)
    if (blockIdx.x == 0 && tid < A) {
      float b = b3[tid];
#pragma unroll
      for (int q = 0; q < A; ++q) b = fmaf(b2[q], W3[q * A + tid], b);
      bb[tid] = b;
    }
    return;
  }
  if (blockIdx.x < 16 + packB) {
    const int d = (blockIdx.x - 16) * 256 + tid;
    const int total = (G + 1) * 64;
    if (d >= total) return;
    const int g = d >> 6, c = d & 63;
    float2 v = make_float2(0.f, 0.f);
    if (g < G) {
      const int b = c >> 5;
      v = out2[(size_t)b * (G * 32) + (size_t)g * 32 + (c & 31)];
    }
    packed[d] = __floats2half2_rn(v.x, v.y);
    return;
  }
  // ---- sort + transpose section: one prep block = one fused block ----
  const int fb = blockIdx.x - 16 - packB;
  __shared__ int S[32 * 33];                 // [slot][gl], +1 pad
  const int half = tid >> 5;                 // 0..7 (row group)
  const int slot = tid & 31;
#pragma unroll
  for (int it = 0; it < 4; ++it) {
    const int gl = it * 8 + half;
    const int r = fb * GPB + gl;
    int v;
    if (r < G) {                             // uniform per 32-lane group
      v = nbr[(size_t)r * K + slot];
#pragma unroll
      for (int kk = 2; kk <= 32; kk <<= 1) {
#pragma unroll
        for (int j = kk >> 1; j >= 1; j >>= 1) {
          const int o = __shfl_xor(v, j);    // j<=16: stays in 32-group
          const bool dir = ((slot & kk) == 0);
          const bool takeMin = (((slot & j) == 0) == dir);
          v = takeMin ? min(v, o) : max(v, o);
        }
      }
    } else {
      v = G;                                 // pad row -> zero row index
    }
    S[slot * 33 + gl] = v;                   // banks (slot+gl)%32: conflict-free
  }
  __syncthreads();
#pragma unroll
  for (int it = 0; it < 4; ++it) {
    const int d = it * 256 + tid;            // d = k*32 + gl
    nbrsT[(size_t)fb * (K * GPB) + d] = S[(d >> 5) * 33 + (d & 31)];
  }
}

// ---- kernel 2: banded gather-sum (sweep-outer) + MFMA epilogue ----
// LDS 17.4 KB (X only; WT read from global -> L1). 8 blocks/CU.
__global__ __launch_bounds__(256, 8) void fused_kernel(
    const __half2* __restrict__ packed, const int* __restrict__ nbrsT,
    const __half* __restrict__ WTg, const float* __restrict__ bb,
    float* __restrict__ y, const int G) {
  __shared__ __half X[64 * XS];   // rows: b*32+gl ; cols: [m(64) | o(64)]

  const int tid = threadIdx.x;
  const int lane = tid & 63;
  const int w = __builtin_amdgcn_readfirstlane(tid >> 6);  // wave id, SGPR
  const int gbase = blockIdx.x * GPB;
  const int gcount = min(GPB, G - gbase);
  const int e = lane & 31;              // element-pair index
  const int rb = (lane >> 5) * 32;      // row base: batch = lane>>5

  const __half2 z = __floats2half2_rn(0.f, 0.f);

  // Residual rows first (one touch per row total; not part of the band).
#pragma unroll
  for (int gg = 0; gg < 8; ++gg) {
    const int gl = w * 8 + gg;
    const int g = (gl < gcount) ? (gbase + gl) : G;
    *(__half2*)&X[(rb + gl) * XS + A + 2 * e] = packed[(size_t)g * 64 + lane];
  }

  // Phase 1: sweep-outer gather. base[k*GPB + gg] are 8 consecutive uniform
  // dwords per step -> s_load_dwordx8. Dual accumulators per gg keep fp16
  // chain depth at 16 and give 16 independent chains of MLP.
  const int* base = nbrsT + (size_t)blockIdx.x * (K * GPB) + w * 8;
  __half2 ma[8], mb[8];
#pragma unroll
  for (int gg = 0; gg < 8; ++gg) { ma[gg] = z; mb[gg] = z; }

#pragma unroll 2
  for (int k = 0; k < K; k += 2) {
#pragma unroll
    for (int gg = 0; gg < 8; ++gg) {
      const int i0 = base[k * GPB + gg];
      ma[gg] = __hadd2(ma[gg], packed[(size_t)i0 * 64 + lane]);
    }
#pragma unroll
    for (int gg = 0; gg < 8; ++gg) {
      const int i1 = base[(k + 1) * GPB + gg];
      mb[gg] = __hadd2(mb[gg], packed[(size_t)i1 * 64 + lane]);
    }
  }

#pragma unroll
  for (int gg = 0; gg < 8; ++gg) {
    const int gl = w * 8 + gg;
    *(__half2*)&X[(rb + gl) * XS + 2 * e] = __hadd2(ma[gg], mb[gg]);
  }
  __syncthreads();

  // Phase 2: Y[64x64] = X[64x128] @ WcatT^T, wave w does rows w*16..w*16+15.
  // A-frag: A[m=lane&15][k=quad*8+j]; B-frag: B[k=quad*8+j][n=lane&15];
  // C/D: col=lane&15, row=quad*4+reg (HW-verified, dtype-independent).
  // B-frags straight from global WTg (16 KB, identical for all blocks -> L1).
  const int quad = lane >> 4;
  const int mn = lane & 15;
  f32x4 acc0 = {0.f, 0.f, 0.f, 0.f};
  f32x4 acc1 = {0.f, 0.f, 0.f, 0.f};
  f32x4 acc2 = {0.f, 0.f, 0.f, 0.f};
  f32x4 acc3 = {0.f, 0.f, 0.f, 0.f};
#pragma unroll
  for (int kt = 0; kt < 4; ++kt) {
    const int ko = kt * 32 + quad * 8;
    const f16x8 a = *(const f16x8*)&X[(w * 16 + mn) * XS + ko];
    const f16x8 b0 = *(const f16x8*)&WTg[(0 * 16 + mn) * 128 + ko];
    acc0 = __builtin_amdgcn_mfma_f32_16x16x32_f16(a, b0, acc0, 0, 0, 0);
    const f16x8 b1 = *(const f16x8*)&WTg[(1 * 16 + mn) * 128 + ko];
    acc1 = __builtin_amdgcn_mfma_f32_16x16x32_f16(a, b1, acc1, 0, 0, 0);
    const f16x8 b2 = *(const f16x8*)&WTg[(2 * 16 + mn) * 128 + ko];
    acc2 = __builtin_amdgcn_mfma_f32_16x16x32_f16(a, b2, acc2, 0, 0, 0);
    const f16x8 b3 = *(const f16x8*)&WTg[(3 * 16 + mn) * 128 + ko];
    acc3 = __builtin_amdgcn_mfma_f32_16x16x32_f16(a, b3, acc3, 0, 0, 0);
  }

  // Store + bias. Row r = w*16 + quad*4 + reg -> (batch r>>5, gl = r&31).
  f32x4 accs[4] = {acc0, acc1, acc2, acc3};
#pragma unroll
  for (int nt = 0; nt < 4; ++nt) {
    const int col = nt * 16 + mn;
    const float bv = bb[col];
#pragma unroll
    for (int rg = 0; rg < 4; ++rg) {
      const int row = w * 16 + quad * 4 + rg;
      const int b = row >> 5, gl = row & 31;
      if (gl < gcount)
        y[((size_t)b * G + (gbase + gl)) * 64 + col] = accs[nt][rg] + bv;
    }
  }
}

extern "C" void kernel_launch(void* const* d_in, const int* in_sizes, int n_in,
                              void* d_out, int out_size, void* d_ws, size_t ws_size,
                              hipStream_t stream) {
  const float* out = (const float*)d_in[0];
  const int*   nbr = (const int*)d_in[1];
  const float* W2  = (const float*)d_in[2];
  const float* b2  = (const float*)d_in[3];
  const float* W3  = (const float*)d_in[4];
  const float* b3  = (const float*)d_in[5];
  float* y = (float*)d_out;
  const int G = in_sizes[1] / K;

  const int blocks = (G + GPB - 1) / GPB;

  // ws: packed rows | WTg (fp16 128x64) | bb (fp32 64) | nbrsT (blocks*1024)
  __half2* packed = (__half2*)d_ws;                       // (G+1)*64 half2
  const size_t packedBytes = (size_t)(G + 1) * 64 * sizeof(__half2);
  __half* WTg = (__half*)((char*)d_ws + packedBytes);     // 8192 halves
  float* bb = (float*)((char*)d_ws + packedBytes + 8192 * sizeof(__half));
  int* nbrsT = (int*)((char*)d_ws + packedBytes + 8192 * sizeof(__half)
                      + 64 * sizeof(float));

  const int packTotal = (G + 1) * 64;
  const int packB = (packTotal + 255) / 256;
  const int sortB = blocks;                 // one prep block per fused block
  prep_kernel<<<16 + packB + sortB, 256, 0, stream>>>(
      W2, b2, W3, b3, WTg, bb, (const float2*)out, packed, nbr, nbrsT, G, packB);

  fused_kernel<<<blocks, 256, 0, stream>>>(packed, nbrsT, WTg, bb, y, G);
}

// Round 5
// 136.749 us; speedup vs baseline: 1.2235x; 1.0170x over previous
//
#include <hip/hip_runtime.h>
#include <hip/hip_fp16.h>

// InteractionBlock, MI355X, round 9.
//
// y = out @ W3 + gathersum(out) @ (W2@W3) + (b2@W3 + b3)
// R8 post-mortem: band sweep works (FETCH 153->82.5 MB, 57->44.8 us) but
// fill rate is only 0.75 fills/cy/XCD vs the 1.1-1.3 port rate -> back to
// concurrency-limited. Occupancy 46% is a GRID artifact: 1563 blocks /
// 256 CU = 6.1 blocks/CU. R9: GPB 32->16 (128-thread 2-wave blocks, LDS
// 8.7 KB, 3125 blocks -> ~12 blocks/CU, ~24 waves/CU, +60% concurrency).
// Residual rows now read from out[] (sequential, block-exclusive) so they
// never disturb the packed band. Everything else unchanged.
// Predict: Occupancy 46->75%, FETCH ~80-95 MB, fused 44.8 -> 30-36 us.

constexpr int A   = 64;    // ao_vals
constexpr int K   = 32;    // neighbors
constexpr int GPB = 16;    // grid points per block (2 waves x 8)
constexpr int XS  = 136;   // LDS row stride in halves (128 data + 8 pad)

typedef _Float16 f16x8 __attribute__((ext_vector_type(8)));
typedef float    f32x4 __attribute__((ext_vector_type(4)));

// ---- kernel 1 (merged prep): three block ranges (256 threads each).
//   [0,16):            WTg[n][k] = (half) concat(W2@W3, W3)[k][n] and
//                      bb = b2@W3 + b3 (fp32)
//   [16,16+packB):     pack out (fp32 [2][G][64]) -> packed ([G+1][64] half2)
//                      Row G is the zero pad row (ws re-poisoned every launch).
//   [16+packB,+sortB): sort 32 rows' neighbor lists ascending (bitonic over
//                      32 lanes) and store transposed per FUSED block (16 g):
//                      nbrsT[fb][k][gl], fb = row/16, gl = row%16.
__global__ void prep_kernel(const float* __restrict__ W2, const float* __restrict__ b2,
                            const float* __restrict__ W3, const float* __restrict__ b3,
                            __half* __restrict__ WTg, float* __restrict__ bb,
                            const float2* __restrict__ out2,
                            __half2* __restrict__ packed,
                            const int* __restrict__ nbr, int* __restrict__ nbrsT,
                            const int G, const int packB) {
  const int tid = threadIdx.x;
  if (blockIdx.x < 16) {
    const int e = blockIdx.x * 256 + tid;           // 0..4095
    const int n = e >> 6, k = e & 63;
    float acc = 0.f;
#pragma unroll
    for (int q = 0; q < A; ++q) acc = fmaf(W2[k * A + q], W3[q * A + n], acc);
    WTg[n * 128 + k]     = __float2half(acc);           // W23 part (k rows 0..63)
    WTg[n * 128 + A + k] = __float2half(W3[k * A + n]); // W3 part (k rows 64..127)
    if (blockIdx.x == 0 && tid < A) {
      float b = b3[tid];
#pragma unroll
      for (int q = 0; q < A; ++q) b = fmaf(b2[q], W3[q * A + tid], b);
      bb[tid] = b;
    }
    return;
  }
  if (blockIdx.x < 16 + packB) {
    const int d = (blockIdx.x - 16) * 256 + tid;
    const int total = (G + 1) * 64;
    if (d >= total) return;
    const int g = d >> 6, c = d & 63;
    float2 v = make_float2(0.f, 0.f);
    if (g < G) {
      const int b = c >> 5;
      v = out2[(size_t)b * (G * 32) + (size_t)g * 32 + (c & 31)];
    }
    packed[d] = __floats2half2_rn(v.x, v.y);
    return;
  }
  // ---- sort + transpose: one prep block = 32 grid rows = 2 fused blocks --
  const int sb = blockIdx.x - 16 - packB;
  __shared__ int S[32 * 33];                 // [slot(k)][local row], +1 pad
  const int half = tid >> 5;                 // 0..7
  const int slot = tid & 31;
#pragma unroll
  for (int it = 0; it < 4; ++it) {
    const int lr = it * 8 + half;            // local row 0..31
    const int r = sb * 32 + lr;
    int v;
    if (r < G) {                             // uniform per 32-lane group
      v = nbr[(size_t)r * K + slot];
#pragma unroll
      for (int kk = 2; kk <= 32; kk <<= 1) {
#pragma unroll
        for (int j = kk >> 1; j >= 1; j >>= 1) {
          const int o = __shfl_xor(v, j);    // j<=16: stays in 32-group
          const bool dir = ((slot & kk) == 0);
          const bool takeMin = (((slot & j) == 0) == dir);
          v = takeMin ? min(v, o) : max(v, o);
        }
      }
    } else {
      v = G;                                 // pad row -> zero row index
    }
    S[slot * 33 + lr] = v;
  }
  __syncthreads();
  // d = fbL*512 + k*16 + gl ; dest nbrsT[sb*1024 + d] is fully coalesced.
#pragma unroll
  for (int it = 0; it < 4; ++it) {
    const int d = it * 256 + tid;
    const int fbL = d >> 9, k = (d >> 4) & 31, gl = d & 15;
    nbrsT[(size_t)sb * 1024 + d] = S[k * 33 + fbL * 16 + gl];
  }
}

// ---- kernel 2: banded gather-sum (sweep-outer) + MFMA epilogue ----
// 128 threads (2 waves), 16 g/block, LDS 8.7 KB -> up to 16 blocks/CU.
__global__ __launch_bounds__(128, 8) void fused_kernel(
    const __half2* __restrict__ packed, const int* __restrict__ nbrsT,
    const float2* __restrict__ out2,
    const __half* __restrict__ WTg, const float* __restrict__ bb,
    float* __restrict__ y, const int G) {
  __shared__ __half X[32 * XS];   // rows: b*16+gl ; cols: [m(64) | o(64)]

  const int tid = threadIdx.x;
  const int lane = tid & 63;
  const int w = __builtin_amdgcn_readfirstlane(tid >> 6);  // wave id 0/1
  const int gbase = blockIdx.x * GPB;
  const int gcount = min(GPB, G - gbase);
  const int e = lane & 31;              // element-pair index
  const int b = lane >> 5;              // batch this half-wave covers
  const int rb = b * 16;                // X row base for this batch

  const __half2 z = __floats2half2_rn(0.f, 0.f);

  // Residual rows straight from out (fp32, sequential, block-exclusive
  // stream -> never touches the packed band).
#pragma unroll
  for (int gg = 0; gg < 8; ++gg) {
    const int gl = w * 8 + gg;
    __half2 o = z;
    if (gl < gcount) {
      const float2 v = out2[(size_t)b * (G * 32) + (size_t)(gbase + gl) * 32 + e];
      o = __floats2half2_rn(v.x, v.y);
    }
    *(__half2*)&X[(rb + gl) * XS + A + 2 * e] = o;
  }

  // Phase 1: sweep-outer gather. base[k*GPB + gg] are 8 consecutive uniform
  // dwords per (k,wave) -> s_load_dwordx8. Dual accumulator banks keep fp16
  // chain depth at 16 and give 16 independent chains; unroll 2 exposes 32
  // loads per scheduling region.
  const int* base = nbrsT + (size_t)blockIdx.x * (K * GPB) + w * 8;
  __half2 ma[8], mb[8];
#pragma unroll
  for (int gg = 0; gg < 8; ++gg) { ma[gg] = z; mb[gg] = z; }

#pragma unroll 2
  for (int k = 0; k < K; k += 2) {
#pragma unroll
    for (int gg = 0; gg < 8; ++gg) {
      const int i0 = base[k * GPB + gg];
      ma[gg] = __hadd2(ma[gg], packed[(size_t)i0 * 64 + lane]);
    }
#pragma unroll
    for (int gg = 0; gg < 8; ++gg) {
      const int i1 = base[(k + 1) * GPB + gg];
      mb[gg] = __hadd2(mb[gg], packed[(size_t)i1 * 64 + lane]);
    }
  }

#pragma unroll
  for (int gg = 0; gg < 8; ++gg) {
    const int gl = w * 8 + gg;
    *(__half2*)&X[(rb + gl) * XS + 2 * e] = __hadd2(ma[gg], mb[gg]);
  }
  __syncthreads();

  // Phase 2: Y[32x64] = X[32x128] @ WcatT^T, wave w does rows w*16..w*16+15.
  // A-frag: A[m=lane&15][k=quad*8+j]; B-frag: B[k=quad*8+j][n=lane&15];
  // C/D: col=lane&15, row=quad*4+reg (HW-verified, dtype-independent).
  // B-frags straight from global WTg (16 KB, identical for all blocks -> L1).
  const int quad = lane >> 4;
  const int mn = lane & 15;
  f32x4 acc0 = {0.f, 0.f, 0.f, 0.f};
  f32x4 acc1 = {0.f, 0.f, 0.f, 0.f};
  f32x4 acc2 = {0.f, 0.f, 0.f, 0.f};
  f32x4 acc3 = {0.f, 0.f, 0.f, 0.f};
#pragma unroll
  for (int kt = 0; kt < 4; ++kt) {
    const int ko = kt * 32 + quad * 8;
    const f16x8 a = *(const f16x8*)&X[(w * 16 + mn) * XS + ko];
    const f16x8 b0 = *(const f16x8*)&WTg[(0 * 16 + mn) * 128 + ko];
    acc0 = __builtin_amdgcn_mfma_f32_16x16x32_f16(a, b0, acc0, 0, 0, 0);
    const f16x8 b1 = *(const f16x8*)&WTg[(1 * 16 + mn) * 128 + ko];
    acc1 = __builtin_amdgcn_mfma_f32_16x16x32_f16(a, b1, acc1, 0, 0, 0);
    const f16x8 b2 = *(const f16x8*)&WTg[(2 * 16 + mn) * 128 + ko];
    acc2 = __builtin_amdgcn_mfma_f32_16x16x32_f16(a, b2, acc2, 0, 0, 0);
    const f16x8 b3 = *(const f16x8*)&WTg[(3 * 16 + mn) * 128 + ko];
    acc3 = __builtin_amdgcn_mfma_f32_16x16x32_f16(a, b3, acc3, 0, 0, 0);
  }

  // Store + bias. Row r = w*16 + quad*4 + reg -> (batch r>>4, gl = r&15).
  f32x4 accs[4] = {acc0, acc1, acc2, acc3};
#pragma unroll
  for (int nt = 0; nt < 4; ++nt) {
    const int col = nt * 16 + mn;
    const float bv = bb[col];
#pragma unroll
    for (int rg = 0; rg < 4; ++rg) {
      const int row = w * 16 + quad * 4 + rg;
      const int bo = row >> 4, gl = row & 15;
      if (gl < gcount)
        y[((size_t)bo * G + (gbase + gl)) * 64 + col] = accs[nt][rg] + bv;
    }
  }
}

extern "C" void kernel_launch(void* const* d_in, const int* in_sizes, int n_in,
                              void* d_out, int out_size, void* d_ws, size_t ws_size,
                              hipStream_t stream) {
  const float* out = (const float*)d_in[0];
  const int*   nbr = (const int*)d_in[1];
  const float* W2  = (const float*)d_in[2];
  const float* b2  = (const float*)d_in[3];
  const float* W3  = (const float*)d_in[4];
  const float* b3  = (const float*)d_in[5];
  float* y = (float*)d_out;
  const int G = in_sizes[1] / K;

  const int blocks = (G + GPB - 1) / GPB;   // fused blocks (16 g each)

  // ws: packed rows | WTg (fp16 128x64) | bb (fp32 64) | nbrsT (blocks*512)
  __half2* packed = (__half2*)d_ws;                       // (G+1)*64 half2
  const size_t packedBytes = (size_t)(G + 1) * 64 * sizeof(__half2);
  __half* WTg = (__half*)((char*)d_ws + packedBytes);     // 8192 halves
  float* bb = (float*)((char*)d_ws + packedBytes + 8192 * sizeof(__half));
  int* nbrsT = (int*)((char*)d_ws + packedBytes + 8192 * sizeof(__half)
                      + 64 * sizeof(float));

  const int packTotal = (G + 1) * 64;
  const int packB = (packTotal + 255) / 256;
  const int sortB = (G + 31) / 32;          // 32 rows per prep block
  prep_kernel<<<16 + packB + sortB, 256, 0, stream>>>(
      W2, b2, W3, b3, WTg, bb, (const float2*)out, packed, nbr, nbrsT, G, packB);

  fused_kernel<<<blocks, 128, 0, stream>>>(packed, nbrsT, (const float2*)out,
                                           WTg, bb, y, G);
}